// Round 2
// baseline (3851.737 us; speedup 1.0000x reference)
//
#include <hip/hip_runtime.h>

#define NQn 40000
#define NTn 10000
#define NCn 50000
#define NTOT 100000
#define DIM 256
#define DEG 8

typedef __bf16 bf16x8 __attribute__((ext_vector_type(8)));
typedef float f32x4 __attribute__((ext_vector_type(4)));

#if __has_builtin(__builtin_amdgcn_exp2f)
#define EXP2F(x) __builtin_amdgcn_exp2f(x)
#else
#define EXP2F(x) exp2f(x)
#endif

static __device__ __forceinline__ float bf2f(unsigned short u) {
    union { unsigned int i; float f; } v; v.i = ((unsigned int)u) << 16; return v.f;
}
static __device__ __forceinline__ unsigned short f2bf(float f) {
    union { unsigned int i; float f; } v; v.f = f;
    unsigned int u = v.i;
    return (unsigned short)((u + 0x7fffu + ((u >> 16) & 1u)) >> 16);
}

// ---------------- elementwise converts ----------------
__global__ void cvt_kernel(const float* __restrict__ in, unsigned short* __restrict__ out, int n) {
    int i = blockIdx.x * 256 + threadIdx.x;
    if (i < n) out[i] = f2bf(in[i]);
}

// W [m][K][NN] fp32 -> WT [m](row nn+nnoff)[K] bf16 with per-m out stride
__global__ void transpose_cvt2(const float* __restrict__ W, unsigned short* __restrict__ WT,
                               int K, int NN, int total, int ostride, int nnoff) {
    int i = blockIdx.x * 256 + threadIdx.x;
    if (i >= total) return;
    int per = K * NN;
    int m = i / per;
    int rem = i - m * per;
    int k = rem / NN;
    int nn = rem - k * NN;
    WT[(size_t)m * ostride + (size_t)(nn + nnoff) * K + k] = f2bf(W[i]);
}

// W1 [m][k=256][ucol=1024] fp32 -> fragment-linear pack for ffn phase1 A-operand:
// P[m][c:32][kk:8][mi:2][lane:64][j:8]; elem (ucol = c*32+mi*16+(lane&15), k = kk*32+(lane>>4)*8+j)
__global__ void pack_w1(const float* __restrict__ W, unsigned short* __restrict__ P, int total) {
    int i = blockIdx.x * 256 + threadIdx.x;
    if (i >= total) return;
    int j  = i & 7;
    int l  = (i >> 3) & 63;
    int mi = (i >> 9) & 1;
    int kk = (i >> 10) & 7;
    int c  = (i >> 13) & 31;
    int m  = i >> 18;
    int ucol = c * 32 + mi * 16 + (l & 15);
    int k    = kk * 32 + (l >> 4) * 8 + j;
    P[i] = f2bf(W[((size_t)m * 256 + k) * 1024 + ucol]);
}

// W2 [m][u=1024][ocol=256] fp32 -> fragment-linear pack for ffn phase2 B-operand:
// P[m][c:32][nf:16][lane:64][j:8]; elem (ocol = nf*16+(lane&15), u = c*32+(lane>>4)*8+j)
__global__ void pack_w2(const float* __restrict__ W, unsigned short* __restrict__ P, int total) {
    int i = blockIdx.x * 256 + threadIdx.x;
    if (i >= total) return;
    int j  = i & 7;
    int l  = (i >> 3) & 63;
    int nf = (i >> 9) & 15;
    int c  = (i >> 13) & 31;
    int m  = i >> 18;
    int ocol = nf * 16 + (l & 15);
    int u    = c * 32 + (l >> 4) * 8 + j;
    P[i] = f2bf(W[((size_t)m * 1024 + u) * 256 + ocol]);
}

// ---------------- GEMM: C[M,N](bf16) = A[M,K](bf16) @ BT[N,K](bf16)^T (+bias, opt relu) ----
__global__ __launch_bounds__(256) void gemm_bt(
    const unsigned short* __restrict__ A,
    const unsigned short* __restrict__ BT,
    const float* __restrict__ bias,
    unsigned short* __restrict__ C,
    int M, int N, int K, int relu)
{
    __shared__ unsigned short a_lds[128 * 32];
    __shared__ unsigned short b_lds[128 * 32];
    const int tid  = threadIdx.x;
    const int w    = tid >> 6;
    const int lane = tid & 63;
    const int rb = blockIdx.x * 128;
    const int cb = blockIdx.y * 128;
    const int wrow = (w & 1) * 64;
    const int wcol = (w >> 1) * 64;
    const int q   = lane >> 4;   // 0..3
    const int r16 = lane & 15;

    f32x4 acc[4][4];
#pragma unroll
    for (int i = 0; i < 4; ++i)
#pragma unroll
        for (int j = 0; j < 4; ++j) acc[i][j] = f32x4{0.f, 0.f, 0.f, 0.f};

    for (int k0 = 0; k0 < K; k0 += 32) {
        __syncthreads();
#pragma unroll
        for (int it = 0; it < 2; ++it) {
            int fl  = it * 256 + tid;
            int row = fl >> 2;
            int c8  = (fl & 3) * 8;
            int arow = rb + row; if (arow > M - 1) arow = M - 1;
            const unsigned short* ga = A  + (size_t)arow * K + k0 + c8;
            const unsigned short* gb = BT + (size_t)(cb + row) * K + k0 + c8;
            unsigned short* la = &a_lds[(size_t)(it * 256 + (tid & ~63)) * 8];
            unsigned short* lb = &b_lds[(size_t)(it * 256 + (tid & ~63)) * 8];
            __builtin_amdgcn_global_load_lds((const __attribute__((address_space(1))) void*)ga,
                                             (__attribute__((address_space(3))) void*)la, 16, 0, 0);
            __builtin_amdgcn_global_load_lds((const __attribute__((address_space(1))) void*)gb,
                                             (__attribute__((address_space(3))) void*)lb, 16, 0, 0);
        }
        __syncthreads();
        bf16x8 af[4], bfr[4];
#pragma unroll
        for (int mi = 0; mi < 4; ++mi)
            af[mi] = *(const bf16x8*)&a_lds[(wrow + mi * 16 + r16) * 32 + q * 8];
#pragma unroll
        for (int ni = 0; ni < 4; ++ni)
            bfr[ni] = *(const bf16x8*)&b_lds[(wcol + ni * 16 + r16) * 32 + q * 8];
#pragma unroll
        for (int mi = 0; mi < 4; ++mi)
#pragma unroll
            for (int ni = 0; ni < 4; ++ni)
                acc[mi][ni] = __builtin_amdgcn_mfma_f32_16x16x32_bf16(af[mi], bfr[ni], acc[mi][ni], 0, 0, 0);
    }

#pragma unroll
    for (int mi = 0; mi < 4; ++mi) {
#pragma unroll
        for (int ni = 0; ni < 4; ++ni) {
            int col = cb + wcol + ni * 16 + r16;
            float bv = bias ? bias[col] : 0.f;
#pragma unroll
            for (int rr = 0; rr < 4; ++rr) {
                int row = rb + wrow + mi * 16 + q * 4 + rr;
                if (row < M) {
                    float v = acc[mi][ni][rr] + bv;
                    if (relu && v < 0.f) v = 0.f;
                    C[(size_t)row * N + col] = f2bf(v);
                }
            }
        }
    }
}

// ---------------- fused FFN: f = relu(h @ W1 + b1) @ W2 + b2 -------------------
// Barrier-free design: W1/W2 fragments loaded DIRECTLY from L2 into VGPRs via
// fragment-linear packed layouts (pack_w1/pack_w2) — no LDS staging of weights,
// no __syncthreads. Only LDS use is a per-wave 2KB u-transpose buffer (same-wave
// lgkmcnt ordering only). h rows stay hoisted in registers; out acc 32x256 fp32.
__global__ __launch_bounds__(256, 2) void ffn_fused(
    const unsigned short* __restrict__ hbp,
    const unsigned short* __restrict__ w1f,
    const float* __restrict__ b1p,
    const unsigned short* __restrict__ w2f,
    const float* __restrict__ b2p,
    unsigned short* __restrict__ fout,
    int M)
{
    __shared__ __align__(16) unsigned short u_lds[4][32 * 32];  // per-wave [row][ucol]

    const int tid  = threadIdx.x;
    const int w    = tid >> 6;
    const int lane = tid & 63;
    const int q    = lane >> 4;   // 0..3
    const int r16  = lane & 15;
    const int row0 = blockIdx.x * 128 + w * 32;

    // hoist h fragments: hf[nj][kk] = rows (row0+nj*16+r16), k-window kk*32 + q*8
    bf16x8 hf[2][8];
#pragma unroll
    for (int nj = 0; nj < 2; ++nj) {
        int rrow = row0 + nj * 16 + r16;
        if (rrow > M - 1) rrow = M - 1;
        const unsigned short* hr = hbp + (size_t)rrow * DIM;
#pragma unroll
        for (int kk = 0; kk < 8; ++kk)
            hf[nj][kk] = *(const bf16x8*)&hr[kk * 32 + q * 8];
    }

    f32x4 acc[2][16];
#pragma unroll
    for (int mj = 0; mj < 2; ++mj)
#pragma unroll
        for (int nf = 0; nf < 16; ++nf) acc[mj][nf] = f32x4{0.f, 0.f, 0.f, 0.f};

    const bf16x8* w1v = (const bf16x8*)w1f + lane;  // frag = 64 x bf16x8; lane's slice
    const bf16x8* w2v = (const bf16x8*)w2f + lane;
    unsigned short* ub = u_lds[w];

    for (int c = 0; c < 32; ++c) {
        // ---- phase 1: u^T = W1c (A, from L2) x h (B, regs)
        f32x4 au[2][2];
#pragma unroll
        for (int mi = 0; mi < 2; ++mi)
#pragma unroll
            for (int nj = 0; nj < 2; ++nj) au[mi][nj] = f32x4{0.f, 0.f, 0.f, 0.f};
#pragma unroll
        for (int kk = 0; kk < 8; ++kk) {
#pragma unroll
            for (int mi = 0; mi < 2; ++mi) {
                bf16x8 a = w1v[(size_t)((c * 8 + kk) * 2 + mi) * 64];
#pragma unroll
                for (int nj = 0; nj < 2; ++nj)
                    au[mi][nj] = __builtin_amdgcn_mfma_f32_16x16x32_bf16(a, hf[nj][kk], au[mi][nj], 0, 0, 0);
            }
        }

        // ---- bias + relu + pack 4 consecutive ucols -> ds_write_b64 (swizzled 16B chunks)
#pragma unroll
        for (int mi = 0; mi < 2; ++mi) {
            float bv[4];
#pragma unroll
            for (int rr = 0; rr < 4; ++rr)
                bv[rr] = b1p[c * 32 + mi * 16 + q * 4 + rr];
#pragma unroll
            for (int nj = 0; nj < 2; ++nj) {
                int row = nj * 16 + r16;
                int sw = (row >> 1) & 3;
                int chunk = (mi * 2 + (q >> 1)) ^ sw;
                int byteoff = row * 64 + chunk * 16 + (q & 1) * 8;
                ushort4 pk;
                pk.x = f2bf(fmaxf(au[mi][nj][0] + bv[0], 0.f));
                pk.y = f2bf(fmaxf(au[mi][nj][1] + bv[1], 0.f));
                pk.z = f2bf(fmaxf(au[mi][nj][2] + bv[2], 0.f));
                pk.w = f2bf(fmaxf(au[mi][nj][3] + bv[3], 0.f));
                *(ushort4*)((char*)ub + byteoff) = pk;
            }
        }

        // ---- phase 2: acc += u (A, via per-wave LDS transpose) x W2c (B, from L2)
        bf16x8 aU[2];
#pragma unroll
        for (int mj = 0; mj < 2; ++mj) {
            int row = mj * 16 + r16;
            int qs = q ^ ((row >> 1) & 3);
            aU[mj] = *(const bf16x8*)((const char*)ub + row * 64 + qs * 16);
        }
#pragma unroll
        for (int nf = 0; nf < 16; ++nf) {
            bf16x8 b = w2v[(size_t)(c * 16 + nf) * 64];
#pragma unroll
            for (int mj = 0; mj < 2; ++mj)
                acc[mj][nf] = __builtin_amdgcn_mfma_f32_16x16x32_bf16(aU[mj], b, acc[mj][nf], 0, 0, 0);
        }
    }

    // ---- epilogue: + b2, store bf16
#pragma unroll
    for (int nf = 0; nf < 16; ++nf) {
        int col = nf * 16 + r16;
        float bv = b2p[col];
#pragma unroll
        for (int mj = 0; mj < 2; ++mj) {
#pragma unroll
            for (int rr = 0; rr < 4; ++rr) {
                int row = row0 + mj * 16 + q * 4 + rr;
                if (row < M) fout[(size_t)row * DIM + col] = f2bf(acc[mj][nf][rr] + bv);
            }
        }
    }
}

// ---------------- attention: one wave per dst node (chunked) ----------------
// kv layout: per node 512 elems: [0,256) = k, [256,512) = v
__device__ __forceinline__ void attn_accum(
    const unsigned short* __restrict__ kvb,
    const int4 s0, const int4 s1, int off_s, int hc,
    const float qv[4], float wv[4], float& z)
{
    const int sidx[8] = {s0.x, s0.y, s0.z, s0.w, s1.x, s1.y, s1.z, s1.w};
    const float CLAMP = 7.2134752f; // 5 * log2(e)
#pragma unroll
    for (int e = 0; e < DEG; ++e) {
        size_t basep = ((size_t)(off_s + sidx[e]) * 512) + hc;
        ushort4 k4 = *(const ushort4*)&kvb[basep];
        float dot = qv[0] * bf2f(k4.x) + qv[1] * bf2f(k4.y) + qv[2] * bf2f(k4.z) + qv[3] * bf2f(k4.w);
        dot += __shfl_xor(dot, 1);
        dot += __shfl_xor(dot, 2);
        dot += __shfl_xor(dot, 4);
        dot = fminf(fmaxf(dot, -CLAMP), CLAMP);
        float wgt = EXP2F(dot);
        ushort4 v4 = *(const ushort4*)&kvb[basep + 256];
        wv[0] += wgt * bf2f(v4.x);
        wv[1] += wgt * bf2f(v4.y);
        wv[2] += wgt * bf2f(v4.z);
        wv[3] += wgt * bf2f(v4.w);
        z += wgt;
    }
}

// qc: chunk-local q rows; writes o01: rows [0,rc)=o0, rows [rc,2rc)=o1
__global__ __launch_bounds__(256) void attn_kernel(
    const unsigned short* __restrict__ qc,
    const unsigned short* __restrict__ kvb,
    const int* __restrict__ src_h,
    const int* __restrict__ src_s,
    const int* __restrict__ src_d,
    unsigned short* __restrict__ o01,
    int rc, int off_d, int off_j)
{
    int widx = (int)((blockIdx.x * 256 + threadIdx.x) >> 6);
    if (widx >= rc) return;
    int lane = threadIdx.x & 63;
    int hc = (lane >> 3) * 32 + (lane & 7) * 4;
    const float PRESCALE = 0.17677669529663687f * 1.4426950408889634f; // 1/sqrt(32)*log2e
    float qv[4];
    {
        ushort4 t4 = *(const ushort4*)&qc[(size_t)widx * DIM + hc];
        qv[0] = bf2f(t4.x) * PRESCALE; qv[1] = bf2f(t4.y) * PRESCALE;
        qv[2] = bf2f(t4.z) * PRESCALE; qv[3] = bf2f(t4.w) * PRESCALE;
    }
    int4 h0 = *(const int4*)&src_h[widx * DEG];
    int4 h1 = *(const int4*)&src_h[widx * DEG + 4];
    int4 ss0 = *(const int4*)&src_s[widx * DEG];
    int4 ss1 = *(const int4*)&src_s[widx * DEG + 4];
    int4 d0 = *(const int4*)&src_d[widx * DEG];
    int4 d1 = *(const int4*)&src_d[widx * DEG + 4];

    size_t ob = (size_t)widx * DIM + hc;

    float wv[4] = {0.f, 0.f, 0.f, 0.f}; float z = 0.f;
    attn_accum(kvb, h0, h1, off_d, hc, qv, wv, z);
    float inv = 1.f / (z + 1e-9f);
    o01[ob + 0] = f2bf(wv[0] * inv); o01[ob + 1] = f2bf(wv[1] * inv);
    o01[ob + 2] = f2bf(wv[2] * inv); o01[ob + 3] = f2bf(wv[3] * inv);

    wv[0] = wv[1] = wv[2] = wv[3] = 0.f; z = 0.f;
    attn_accum(kvb, ss0, ss1, off_j, hc, qv, wv, z);
    attn_accum(kvb, d0, d1, off_d, hc, qv, wv, z);
    inv = 1.f / (z + 1e-9f);
    size_t ob1 = ob + (size_t)rc * DIM;
    o01[ob1 + 0] = f2bf(wv[0] * inv); o01[ob1 + 1] = f2bf(wv[1] * inv);
    o01[ob1 + 2] = f2bf(wv[2] * inv); o01[ob1 + 3] = f2bf(wv[3] * inv);
}

// ---------------- LN1 over 2rc rows (both metapaths share the x residual) ----------------
__global__ __launch_bounds__(256) void ln1_kernel(
    const float* __restrict__ xres_f, const unsigned short* __restrict__ xres_b,
    const unsigned short* __restrict__ t,
    const float* __restrict__ g, const float* __restrict__ b,
    unsigned short* __restrict__ hb,
    int rc, int goff)
{
    int row = (int)((blockIdx.x * 256 + threadIdx.x) >> 6);
    int n2 = 2 * rc;
    if (row >= n2) return;
    int lane = threadIdx.x & 63;
    int dstrow = row < rc ? row : row - rc;
    size_t gbase = (size_t)(goff + dstrow) * DIM + lane * 4;
    size_t lbase = (size_t)row * DIM + lane * 4;
    float pre[4];
#pragma unroll
    for (int j = 0; j < 4; ++j) {
        float xr = xres_f ? xres_f[gbase + j] : bf2f(xres_b[gbase + j]);
        pre[j] = xr + bf2f(t[lbase + j]);
    }
    float s = 0.f, sq = 0.f;
#pragma unroll
    for (int j = 0; j < 4; ++j) { s += pre[j]; sq += pre[j] * pre[j]; }
#pragma unroll
    for (int m = 1; m < 64; m <<= 1) { s += __shfl_xor(s, m); sq += __shfl_xor(sq, m); }
    float mean = s * (1.f / 256.f);
    float var = sq * (1.f / 256.f) - mean * mean;
    float rstd = rsqrtf(var + 1e-5f);
#pragma unroll
    for (int j = 0; j < 4; ++j) {
        int col = lane * 4 + j;
        float hv = (pre[j] - mean) * rstd * g[col] + b[col];
        hb[lbase + j] = f2bf(hv);
    }
}

// ---------------- LN2 + metapath mean: wave per dst row, reads both halves ----------------
__global__ __launch_bounds__(256) void ln2_final(
    const unsigned short* __restrict__ hb, const unsigned short* __restrict__ f,
    const float* __restrict__ g, const float* __restrict__ b,
    unsigned short* __restrict__ xb_out,   // layer0: next-layer bf16 x
    float* __restrict__ fout,              // layer1: d_out
    int rc, int goff)
{
    int row = (int)((blockIdx.x * 256 + threadIdx.x) >> 6);
    if (row >= rc) return;
    int lane = threadIdx.x & 63;
    size_t lb0 = (size_t)row * DIM + lane * 4;
    size_t lb1 = (size_t)(rc + row) * DIM + lane * 4;
    size_t gbase = (size_t)(goff + row) * DIM + lane * 4;
    float p0[4], p1[4];
#pragma unroll
    for (int j = 0; j < 4; ++j) {
        p0[j] = bf2f(hb[lb0 + j]) + bf2f(f[lb0 + j]);
        p1[j] = bf2f(hb[lb1 + j]) + bf2f(f[lb1 + j]);
    }
    float s0 = 0.f, q0 = 0.f, s1 = 0.f, q1 = 0.f;
#pragma unroll
    for (int j = 0; j < 4; ++j) {
        s0 += p0[j]; q0 += p0[j] * p0[j];
        s1 += p1[j]; q1 += p1[j] * p1[j];
    }
#pragma unroll
    for (int m = 1; m < 64; m <<= 1) {
        s0 += __shfl_xor(s0, m); q0 += __shfl_xor(q0, m);
        s1 += __shfl_xor(s1, m); q1 += __shfl_xor(q1, m);
    }
    float m0 = s0 * (1.f / 256.f), m1 = s1 * (1.f / 256.f);
    float r0 = rsqrtf(q0 * (1.f / 256.f) - m0 * m0 + 1e-5f);
    float r1 = rsqrtf(q1 * (1.f / 256.f) - m1 * m1 + 1e-5f);
#pragma unroll
    for (int j = 0; j < 4; ++j) {
        int col = lane * 4 + j;
        float ga = g[col], ba = b[col];
        float h20 = (p0[j] - m0) * r0 * ga + ba;
        float h21 = (p1[j] - m1) * r1 * ga + ba;
        float val = (h20 + h21) * 0.5f;
        if (xb_out) xb_out[gbase + j] = f2bf(val);
        if (fout)   fout[gbase + j] = val;
    }
}

// ---------------- host ----------------
extern "C" void kernel_launch(void* const* d_in, const int* in_sizes, int n_in,
                              void* d_out, int out_size, void* d_ws, size_t ws_size,
                              hipStream_t stream) {
    const float* x0  = (const float*)d_in[0];
    const float* Wq  = (const float*)d_in[1];
    const float* bq  = (const float*)d_in[2];
    const float* Wk  = (const float*)d_in[3];
    const float* Wv  = (const float*)d_in[4];
    const float* Wo  = (const float*)d_in[5];
    const float* bo  = (const float*)d_in[6];
    const float* g1  = (const float*)d_in[7];
    const float* b1  = (const float*)d_in[8];
    const float* W1  = (const float*)d_in[9];
    const float* bf1 = (const float*)d_in[10];
    const float* W2  = (const float*)d_in[11];
    const float* bf2 = (const float*)d_in[12];
    const float* g2  = (const float*)d_in[13];
    const float* b2  = (const float*)d_in[14];
    const int* hs[3]  = {(const int*)d_in[15], (const int*)d_in[21], (const int*)d_in[27]};
    const int* ssx[3] = {(const int*)d_in[17], (const int*)d_in[23], (const int*)d_in[29]};
    const int* dsx[3] = {(const int*)d_in[19], (const int*)d_in[25], (const int*)d_in[31]};
    float* out = (float*)d_out;

    char* base = (char*)d_ws;
    size_t off = 0;
    auto carve = [&](size_t bytes) -> void* {
        void* r = base + off;
        off += (bytes + 255) & ~(size_t)255;
        return r;
    };
    // persistent: ~163 MB
    unsigned short* WqT  = (unsigned short*)carve((size_t)6 * 65536 * 2);
    unsigned short* WkvT = (unsigned short*)carve((size_t)6 * 131072 * 2);
    unsigned short* WoT  = (unsigned short*)carve((size_t)6 * 65536 * 2);
    unsigned short* W1F  = (unsigned short*)carve((size_t)6 * 262144 * 2);
    unsigned short* W2F  = (unsigned short*)carve((size_t)6 * 262144 * 2);
    unsigned short* xb   = (unsigned short*)carve((size_t)NTOT * DIM * 2);
    unsigned short* kvb  = (unsigned short*)carve((size_t)NTOT * 512 * 2);

    // chunk size: 3072 B per dst row (o01 1024 + tf 1024 + hb 1024; qc aliases tf)
    size_t avail = (ws_size > off + 8192) ? (ws_size - off - 8192) : 0;
    long rmax = (long)(avail / 3072);
    int R = (int)(rmax & ~63L);
    if (R < 1024)  R = 1024;
    if (R > 50048) R = 50048;

    unsigned short* o01  = (unsigned short*)carve((size_t)2 * R * DIM * 2);
    unsigned short* tfb  = (unsigned short*)carve((size_t)2 * R * DIM * 2);
    unsigned short* hbb  = (unsigned short*)carve((size_t)2 * R * DIM * 2);
    unsigned short* qc   = tfb; // alias: qc dead before tf is written

    // weight prep + input cast (graph-safe, deterministic)
    {
        int tot = 6 * 65536;
        dim3 g((tot + 255) / 256);
        transpose_cvt2<<<g, 256, 0, stream>>>(Wq, WqT, 256, 256, tot, 65536, 0);
        transpose_cvt2<<<g, 256, 0, stream>>>(Wk, WkvT, 256, 256, tot, 131072, 0);
        transpose_cvt2<<<g, 256, 0, stream>>>(Wv, WkvT, 256, 256, tot, 131072, 256);
        transpose_cvt2<<<g, 256, 0, stream>>>(Wo, WoT, 256, 256, tot, 65536, 0);
        int tot2 = 6 * 262144;
        dim3 g2d((tot2 + 255) / 256);
        pack_w1<<<g2d, 256, 0, stream>>>(W1, W1F, tot2);
        pack_w2<<<g2d, 256, 0, stream>>>(W2, W2F, tot2);
        int totx = NTOT * DIM;
        cvt_kernel<<<dim3((totx + 255) / 256), 256, 0, stream>>>(x0, xb, totx);
    }

    const int offs[3] = {0, NQn, NQn + NTn};
    const int ns[3]   = {NQn, NTn, NCn};
    const int ends[3] = {1, 2, 0};

    auto gemm = [&](const unsigned short* A, const unsigned short* BT, const float* bias,
                    unsigned short* C, int M, int N, int K, int relu) {
        dim3 g((M + 127) / 128, N / 128);
        gemm_bt<<<g, 256, 0, stream>>>(A, BT, bias, C, M, N, K, relu);
    };

    for (int l = 0; l < 2; ++l) {
        // fused K|V for all types
        for (int i = 0; i < 3; ++i) {
            int m = l * 3 + i;
            gemm(xb + (size_t)offs[i] * DIM, WkvT + (size_t)m * 131072, nullptr,
                 kvb + (size_t)offs[i] * 512, ns[i], 512, 256, 0);
        }
        // per-type, chunked pipeline (6 launches/chunk)
        for (int i = 0; i < 3; ++i) {
            int m = l * 3 + i;
            for (int r0 = 0; r0 < ns[i]; r0 += R) {
                int rc = ns[i] - r0 < R ? ns[i] - r0 : R;
                int goff = offs[i] + r0;
                gemm(xb + (size_t)goff * DIM, WqT + (size_t)m * 65536, bq + (size_t)m * 256,
                     qc, rc, 256, 256, 0);
                attn_kernel<<<dim3((rc + 3) / 4), 256, 0, stream>>>(
                    qc, kvb,
                    hs[i] + (size_t)r0 * DEG, ssx[i] + (size_t)r0 * DEG, dsx[i] + (size_t)r0 * DEG,
                    o01, rc, offs[i], offs[ends[i]]);
                gemm(o01, WoT + (size_t)m * 65536, bo + (size_t)m * 256, tfb, 2 * rc, 256, 256, 0);
                ln1_kernel<<<dim3((2 * rc + 3) / 4), 256, 0, stream>>>(
                    l == 0 ? x0 : nullptr, l == 0 ? nullptr : xb, tfb,
                    g1 + (size_t)m * 256, b1 + (size_t)m * 256, hbb, rc, goff);
                ffn_fused<<<dim3((2 * rc + 127) / 128), 256, 0, stream>>>(
                    hbb, W1F + (size_t)m * 262144, bf1 + (size_t)m * 1024,
                    W2F + (size_t)m * 262144, bf2 + (size_t)m * 256, tfb, 2 * rc);
                ln2_final<<<dim3((rc + 3) / 4), 256, 0, stream>>>(
                    hbb, tfb, g2 + (size_t)m * 256, b2 + (size_t)m * 256,
                    l == 0 ? xb : nullptr, l == 1 ? out : nullptr,
                    rc, goff);
            }
        }
    }
}

// Round 5
// 2651.399 us; speedup vs baseline: 1.4527x; 1.4527x over previous
//
#include <hip/hip_runtime.h>

#define NQn 40000
#define NTn 10000
#define NCn 50000
#define NTOT 100000
#define DIM 256
#define DEG 8

typedef __bf16 bf16x8 __attribute__((ext_vector_type(8)));
typedef float f32x4 __attribute__((ext_vector_type(4)));

#if __has_builtin(__builtin_amdgcn_exp2f)
#define EXP2F(x) __builtin_amdgcn_exp2f(x)
#else
#define EXP2F(x) exp2f(x)
#endif

static __device__ __forceinline__ float bf2f(unsigned short u) {
    union { unsigned int i; float f; } v; v.i = ((unsigned int)u) << 16; return v.f;
}
static __device__ __forceinline__ unsigned short f2bf(float f) {
    union { unsigned int i; float f; } v; v.f = f;
    unsigned int u = v.i;
    return (unsigned short)((u + 0x7fffu + ((u >> 16) & 1u)) >> 16);
}

// ---------------- elementwise converts ----------------
__global__ void cvt_kernel(const float* __restrict__ in, unsigned short* __restrict__ out, int n) {
    int i = blockIdx.x * 256 + threadIdx.x;
    if (i < n) out[i] = f2bf(in[i]);
}

// W [m][K][NN] fp32 -> WT [m](row nn+nnoff)[K] bf16 with per-m out stride
__global__ void transpose_cvt2(const float* __restrict__ W, unsigned short* __restrict__ WT,
                               int K, int NN, int total, int ostride, int nnoff) {
    int i = blockIdx.x * 256 + threadIdx.x;
    if (i >= total) return;
    int per = K * NN;
    int m = i / per;
    int rem = i - m * per;
    int k = rem / NN;
    int nn = rem - k * NN;
    WT[(size_t)m * ostride + (size_t)(nn + nnoff) * K + k] = f2bf(W[i]);
}

// W1 [m][k=256][ucol=1024] fp32 -> fragment-linear pack for ffn phase1 A-operand:
// P[m][c:32][kk:8][mi:2][lane:64][j:8]; elem (ucol = c*32+mi*16+(lane&15), k = kk*32+(lane>>4)*8+j)
__global__ void pack_w1(const float* __restrict__ W, unsigned short* __restrict__ P, int total) {
    int i = blockIdx.x * 256 + threadIdx.x;
    if (i >= total) return;
    int j  = i & 7;
    int l  = (i >> 3) & 63;
    int mi = (i >> 9) & 1;
    int kk = (i >> 10) & 7;
    int c  = (i >> 13) & 31;
    int m  = i >> 18;
    int ucol = c * 32 + mi * 16 + (l & 15);
    int k    = kk * 32 + (l >> 4) * 8 + j;
    P[i] = f2bf(W[((size_t)m * 256 + k) * 1024 + ucol]);
}

// W2 [m][u=1024][ocol=256] fp32 -> fragment-linear pack for ffn phase2 B-operand:
// P[m][c:32][nf:16][lane:64][j:8]; elem (ocol = nf*16+(lane&15), u = c*32+(lane>>4)*8+j)
__global__ void pack_w2(const float* __restrict__ W, unsigned short* __restrict__ P, int total) {
    int i = blockIdx.x * 256 + threadIdx.x;
    if (i >= total) return;
    int j  = i & 7;
    int l  = (i >> 3) & 63;
    int nf = (i >> 9) & 15;
    int c  = (i >> 13) & 31;
    int m  = i >> 18;
    int ocol = nf * 16 + (l & 15);
    int u    = c * 32 + (l >> 4) * 8 + j;
    P[i] = f2bf(W[((size_t)m * 1024 + u) * 256 + ocol]);
}

// ---------------- GEMM: C[M,N](bf16) = A[M,K](bf16) @ BT[N,K](bf16)^T (+bias, opt relu) ----
__global__ __launch_bounds__(256) void gemm_bt(
    const unsigned short* __restrict__ A,
    const unsigned short* __restrict__ BT,
    const float* __restrict__ bias,
    unsigned short* __restrict__ C,
    int M, int N, int K, int relu)
{
    __shared__ unsigned short a_lds[128 * 32];
    __shared__ unsigned short b_lds[128 * 32];
    const int tid  = threadIdx.x;
    const int w    = tid >> 6;
    const int lane = tid & 63;
    const int rb = blockIdx.x * 128;
    const int cb = blockIdx.y * 128;
    const int wrow = (w & 1) * 64;
    const int wcol = (w >> 1) * 64;
    const int q   = lane >> 4;   // 0..3
    const int r16 = lane & 15;

    f32x4 acc[4][4];
#pragma unroll
    for (int i = 0; i < 4; ++i)
#pragma unroll
        for (int j = 0; j < 4; ++j) acc[i][j] = f32x4{0.f, 0.f, 0.f, 0.f};

    for (int k0 = 0; k0 < K; k0 += 32) {
        __syncthreads();
#pragma unroll
        for (int it = 0; it < 2; ++it) {
            int fl  = it * 256 + tid;
            int row = fl >> 2;
            int c8  = (fl & 3) * 8;
            int arow = rb + row; if (arow > M - 1) arow = M - 1;
            const unsigned short* ga = A  + (size_t)arow * K + k0 + c8;
            const unsigned short* gb = BT + (size_t)(cb + row) * K + k0 + c8;
            unsigned short* la = &a_lds[(size_t)(it * 256 + (tid & ~63)) * 8];
            unsigned short* lb = &b_lds[(size_t)(it * 256 + (tid & ~63)) * 8];
            __builtin_amdgcn_global_load_lds((const __attribute__((address_space(1))) void*)ga,
                                             (__attribute__((address_space(3))) void*)la, 16, 0, 0);
            __builtin_amdgcn_global_load_lds((const __attribute__((address_space(1))) void*)gb,
                                             (__attribute__((address_space(3))) void*)lb, 16, 0, 0);
        }
        __syncthreads();
        bf16x8 af[4], bfr[4];
#pragma unroll
        for (int mi = 0; mi < 4; ++mi)
            af[mi] = *(const bf16x8*)&a_lds[(wrow + mi * 16 + r16) * 32 + q * 8];
#pragma unroll
        for (int ni = 0; ni < 4; ++ni)
            bfr[ni] = *(const bf16x8*)&b_lds[(wcol + ni * 16 + r16) * 32 + q * 8];
#pragma unroll
        for (int mi = 0; mi < 4; ++mi)
#pragma unroll
            for (int ni = 0; ni < 4; ++ni)
                acc[mi][ni] = __builtin_amdgcn_mfma_f32_16x16x32_bf16(af[mi], bfr[ni], acc[mi][ni], 0, 0, 0);
    }

#pragma unroll
    for (int mi = 0; mi < 4; ++mi) {
#pragma unroll
        for (int ni = 0; ni < 4; ++ni) {
            int col = cb + wcol + ni * 16 + r16;
            float bv = bias ? bias[col] : 0.f;
#pragma unroll
            for (int rr = 0; rr < 4; ++rr) {
                int row = rb + wrow + mi * 16 + q * 4 + rr;
                if (row < M) {
                    float v = acc[mi][ni][rr] + bv;
                    if (relu && v < 0.f) v = 0.f;
                    C[(size_t)row * N + col] = f2bf(v);
                }
            }
        }
    }
}

// ---------------- fused FFN: f = relu(h @ W1 + b1) @ W2 + b2 -------------------
// Plain-HIP schedule (no inline asm, no raw barriers): per 32-ucol chunk,
// single-buffered LDS staging with the proven gemm_bt 2-barrier structure.
// Weights staged from fragment-linear packs (pack_w1/pack_w2) so every frag
// ds_read_b128 is consecutive-lane/consecutive-16B = bank-conflict-free, no
// swizzle. b1 preloaded to LDS (zero in-loop global loads). 44KB LDS ->
// 3 blocks/CU for TLP. u-transpose via per-wave 2KB LDS (round-1 verified).
__global__ __launch_bounds__(256, 2) void ffn_fused(
    const unsigned short* __restrict__ hbp,
    const unsigned short* __restrict__ w1f,
    const float* __restrict__ b1p,
    const unsigned short* __restrict__ w2f,
    const float* __restrict__ b2p,
    unsigned short* __restrict__ fout,
    int M)
{
    __shared__ __align__(16) unsigned short w1_lds[8192];   // 16KB: chunk frag-linear
    __shared__ __align__(16) unsigned short w2_lds[8192];   // 16KB
    __shared__ __align__(16) unsigned short u_lds[4][1024]; // per-wave [row][ucol] 8KB
    __shared__ __align__(16) float b1_lds[1024];            // 4KB

    const int tid  = threadIdx.x;
    const int w    = tid >> 6;
    const int lane = tid & 63;
    const int q    = lane >> 4;   // 0..3
    const int r16  = lane & 15;
    const int row0 = blockIdx.x * 128 + w * 32;

    // ---- prologue: hoist h fragments (global->reg), stage b1 (global->LDS)
    bf16x8 hf[2][8];
#pragma unroll
    for (int nj = 0; nj < 2; ++nj) {
        int rrow = row0 + nj * 16 + r16;
        if (rrow > M - 1) rrow = M - 1;
        const unsigned short* hr = hbp + (size_t)rrow * DIM;
#pragma unroll
        for (int kk = 0; kk < 8; ++kk)
            hf[nj][kk] = *(const bf16x8*)&hr[kk * 32 + q * 8];
    }
    {
        const float* g = b1p + tid * 4;                      // 1024 floats, 16B/lane
        float* l = &b1_lds[(tid & ~63) * 4];                 // wave-uniform dest base
        __builtin_amdgcn_global_load_lds((const __attribute__((address_space(1))) void*)g,
                                         (__attribute__((address_space(3))) void*)l, 16, 0, 0);
    }

    f32x4 acc[2][16];
#pragma unroll
    for (int mj = 0; mj < 2; ++mj)
#pragma unroll
        for (int nf = 0; nf < 16; ++nf) acc[mj][nf] = f32x4{0.f, 0.f, 0.f, 0.f};

    unsigned short* ub = u_lds[w];

    for (int c = 0; c < 32; ++c) {
        __syncthreads();   // all waves done reading previous chunk's LDS
#pragma unroll
        for (int it = 0; it < 4; ++it) {
            int fl = it * 256 + tid;
            const unsigned short* g = w1f + (size_t)c * 8192 + (size_t)fl * 8;
            unsigned short* l = &w1_lds[(size_t)(it * 256 + (tid & ~63)) * 8];
            __builtin_amdgcn_global_load_lds((const __attribute__((address_space(1))) void*)g,
                                             (__attribute__((address_space(3))) void*)l, 16, 0, 0);
        }
#pragma unroll
        for (int it = 0; it < 4; ++it) {
            int fl = it * 256 + tid;
            const unsigned short* g = w2f + (size_t)c * 8192 + (size_t)fl * 8;
            unsigned short* l = &w2_lds[(size_t)(it * 256 + (tid & ~63)) * 8];
            __builtin_amdgcn_global_load_lds((const __attribute__((address_space(1))) void*)g,
                                             (__attribute__((address_space(3))) void*)l, 16, 0, 0);
        }
        __syncthreads();   // staged chunk visible (compiler drains vmcnt here)

        // ---- phase 1: u^T = W1c (A, frag-linear LDS) x h (B, regs)
        f32x4 au[2][2];
#pragma unroll
        for (int mi = 0; mi < 2; ++mi)
#pragma unroll
            for (int nj = 0; nj < 2; ++nj) au[mi][nj] = f32x4{0.f, 0.f, 0.f, 0.f};
#pragma unroll
        for (int kk = 0; kk < 8; ++kk) {
#pragma unroll
            for (int mi = 0; mi < 2; ++mi) {
                bf16x8 a = *(const bf16x8*)&w1_lds[(size_t)((kk * 2 + mi) * 64 + lane) * 8];
#pragma unroll
                for (int nj = 0; nj < 2; ++nj)
                    au[mi][nj] = __builtin_amdgcn_mfma_f32_16x16x32_bf16(a, hf[nj][kk], au[mi][nj], 0, 0, 0);
            }
        }

        // ---- bias (LDS) + relu + pack 4 consecutive ucols -> ds_write_b64 (swizzled 16B chunks)
#pragma unroll
        for (int mi = 0; mi < 2; ++mi) {
            f32x4 bv = *(const f32x4*)&b1_lds[c * 32 + mi * 16 + q * 4];
#pragma unroll
            for (int nj = 0; nj < 2; ++nj) {
                int row = nj * 16 + r16;
                int sw = (row >> 1) & 3;
                int chunk = (mi * 2 + (q >> 1)) ^ sw;
                int byteoff = row * 64 + chunk * 16 + (q & 1) * 8;
                ushort4 pk;
                pk.x = f2bf(fmaxf(au[mi][nj][0] + bv[0], 0.f));
                pk.y = f2bf(fmaxf(au[mi][nj][1] + bv[1], 0.f));
                pk.z = f2bf(fmaxf(au[mi][nj][2] + bv[2], 0.f));
                pk.w = f2bf(fmaxf(au[mi][nj][3] + bv[3], 0.f));
                *(ushort4*)((char*)ub + byteoff) = pk;
            }
        }

        // ---- phase 2: acc += u (A, per-wave LDS transpose) x W2c (B, frag-linear LDS)
        bf16x8 aU[2];
#pragma unroll
        for (int mj = 0; mj < 2; ++mj) {
            int row = mj * 16 + r16;
            int qs = q ^ ((row >> 1) & 3);
            aU[mj] = *(const bf16x8*)((const char*)ub + row * 64 + qs * 16);
        }
#pragma unroll
        for (int nf = 0; nf < 16; ++nf) {
            bf16x8 b = *(const bf16x8*)&w2_lds[(size_t)(nf * 64 + lane) * 8];
#pragma unroll
            for (int mj = 0; mj < 2; ++mj)
                acc[mj][nf] = __builtin_amdgcn_mfma_f32_16x16x32_bf16(aU[mj], b, acc[mj][nf], 0, 0, 0);
        }
    }

    // ---- epilogue: + b2, store bf16
#pragma unroll
    for (int nf = 0; nf < 16; ++nf) {
        int col = nf * 16 + r16;
        float bv = b2p[col];
#pragma unroll
        for (int mj = 0; mj < 2; ++mj) {
#pragma unroll
            for (int rr = 0; rr < 4; ++rr) {
                int row = row0 + mj * 16 + q * 4 + rr;
                if (row < M) fout[(size_t)row * DIM + col] = f2bf(acc[mj][nf][rr] + bv);
            }
        }
    }
}

// ---------------- attention: one wave per dst node (chunked) ----------------
// kv layout: per node 512 elems: [0,256) = k, [256,512) = v
__device__ __forceinline__ void attn_accum(
    const unsigned short* __restrict__ kvb,
    const int4 s0, const int4 s1, int off_s, int hc,
    const float qv[4], float wv[4], float& z)
{
    const int sidx[8] = {s0.x, s0.y, s0.z, s0.w, s1.x, s1.y, s1.z, s1.w};
    const float CLAMP = 7.2134752f; // 5 * log2(e)
#pragma unroll
    for (int e = 0; e < DEG; ++e) {
        size_t basep = ((size_t)(off_s + sidx[e]) * 512) + hc;
        ushort4 k4 = *(const ushort4*)&kvb[basep];
        float dot = qv[0] * bf2f(k4.x) + qv[1] * bf2f(k4.y) + qv[2] * bf2f(k4.z) + qv[3] * bf2f(k4.w);
        dot += __shfl_xor(dot, 1);
        dot += __shfl_xor(dot, 2);
        dot += __shfl_xor(dot, 4);
        dot = fminf(fmaxf(dot, -CLAMP), CLAMP);
        float wgt = EXP2F(dot);
        ushort4 v4 = *(const ushort4*)&kvb[basep + 256];
        wv[0] += wgt * bf2f(v4.x);
        wv[1] += wgt * bf2f(v4.y);
        wv[2] += wgt * bf2f(v4.z);
        wv[3] += wgt * bf2f(v4.w);
        z += wgt;
    }
}

// qc: chunk-local q rows; writes o01: rows [0,rc)=o0, rows [rc,2rc)=o1
__global__ __launch_bounds__(256) void attn_kernel(
    const unsigned short* __restrict__ qc,
    const unsigned short* __restrict__ kvb,
    const int* __restrict__ src_h,
    const int* __restrict__ src_s,
    const int* __restrict__ src_d,
    unsigned short* __restrict__ o01,
    int rc, int off_d, int off_j)
{
    int widx = (int)((blockIdx.x * 256 + threadIdx.x) >> 6);
    if (widx >= rc) return;
    int lane = threadIdx.x & 63;
    int hc = (lane >> 3) * 32 + (lane & 7) * 4;
    const float PRESCALE = 0.17677669529663687f * 1.4426950408889634f; // 1/sqrt(32)*log2e
    float qv[4];
    {
        ushort4 t4 = *(const ushort4*)&qc[(size_t)widx * DIM + hc];
        qv[0] = bf2f(t4.x) * PRESCALE; qv[1] = bf2f(t4.y) * PRESCALE;
        qv[2] = bf2f(t4.z) * PRESCALE; qv[3] = bf2f(t4.w) * PRESCALE;
    }
    int4 h0 = *(const int4*)&src_h[widx * DEG];
    int4 h1 = *(const int4*)&src_h[widx * DEG + 4];
    int4 ss0 = *(const int4*)&src_s[widx * DEG];
    int4 ss1 = *(const int4*)&src_s[widx * DEG + 4];
    int4 d0 = *(const int4*)&src_d[widx * DEG];
    int4 d1 = *(const int4*)&src_d[widx * DEG + 4];

    size_t ob = (size_t)widx * DIM + hc;

    float wv[4] = {0.f, 0.f, 0.f, 0.f}; float z = 0.f;
    attn_accum(kvb, h0, h1, off_d, hc, qv, wv, z);
    float inv = 1.f / (z + 1e-9f);
    o01[ob + 0] = f2bf(wv[0] * inv); o01[ob + 1] = f2bf(wv[1] * inv);
    o01[ob + 2] = f2bf(wv[2] * inv); o01[ob + 3] = f2bf(wv[3] * inv);

    wv[0] = wv[1] = wv[2] = wv[3] = 0.f; z = 0.f;
    attn_accum(kvb, ss0, ss1, off_j, hc, qv, wv, z);
    attn_accum(kvb, d0, d1, off_d, hc, qv, wv, z);
    inv = 1.f / (z + 1e-9f);
    size_t ob1 = ob + (size_t)rc * DIM;
    o01[ob1 + 0] = f2bf(wv[0] * inv); o01[ob1 + 1] = f2bf(wv[1] * inv);
    o01[ob1 + 2] = f2bf(wv[2] * inv); o01[ob1 + 3] = f2bf(wv[3] * inv);
}

// ---------------- LN1 over 2rc rows (both metapaths share the x residual) ----------------
__global__ __launch_bounds__(256) void ln1_kernel(
    const float* __restrict__ xres_f, const unsigned short* __restrict__ xres_b,
    const unsigned short* __restrict__ t,
    const float* __restrict__ g, const float* __restrict__ b,
    unsigned short* __restrict__ hb,
    int rc, int goff)
{
    int row = (int)((blockIdx.x * 256 + threadIdx.x) >> 6);
    int n2 = 2 * rc;
    if (row >= n2) return;
    int lane = threadIdx.x & 63;
    int dstrow = row < rc ? row : row - rc;
    size_t gbase = (size_t)(goff + dstrow) * DIM + lane * 4;
    size_t lbase = (size_t)row * DIM + lane * 4;
    float pre[4];
#pragma unroll
    for (int j = 0; j < 4; ++j) {
        float xr = xres_f ? xres_f[gbase + j] : bf2f(xres_b[gbase + j]);
        pre[j] = xr + bf2f(t[lbase + j]);
    }
    float s = 0.f, sq = 0.f;
#pragma unroll
    for (int j = 0; j < 4; ++j) { s += pre[j]; sq += pre[j] * pre[j]; }
#pragma unroll
    for (int m = 1; m < 64; m <<= 1) { s += __shfl_xor(s, m); sq += __shfl_xor(sq, m); }
    float mean = s * (1.f / 256.f);
    float var = sq * (1.f / 256.f) - mean * mean;
    float rstd = rsqrtf(var + 1e-5f);
#pragma unroll
    for (int j = 0; j < 4; ++j) {
        int col = lane * 4 + j;
        float hv = (pre[j] - mean) * rstd * g[col] + b[col];
        hb[lbase + j] = f2bf(hv);
    }
}

// ---------------- LN2 + metapath mean: wave per dst row, reads both halves ----------------
__global__ __launch_bounds__(256) void ln2_final(
    const unsigned short* __restrict__ hb, const unsigned short* __restrict__ f,
    const float* __restrict__ g, const float* __restrict__ b,
    unsigned short* __restrict__ xb_out,   // layer0: next-layer bf16 x
    float* __restrict__ fout,              // layer1: d_out
    int rc, int goff)
{
    int row = (int)((blockIdx.x * 256 + threadIdx.x) >> 6);
    if (row >= rc) return;
    int lane = threadIdx.x & 63;
    size_t lb0 = (size_t)row * DIM + lane * 4;
    size_t lb1 = (size_t)(rc + row) * DIM + lane * 4;
    size_t gbase = (size_t)(goff + row) * DIM + lane * 4;
    float p0[4], p1[4];
#pragma unroll
    for (int j = 0; j < 4; ++j) {
        p0[j] = bf2f(hb[lb0 + j]) + bf2f(f[lb0 + j]);
        p1[j] = bf2f(hb[lb1 + j]) + bf2f(f[lb1 + j]);
    }
    float s0 = 0.f, q0 = 0.f, s1 = 0.f, q1 = 0.f;
#pragma unroll
    for (int j = 0; j < 4; ++j) {
        s0 += p0[j]; q0 += p0[j] * p0[j];
        s1 += p1[j]; q1 += p1[j] * p1[j];
    }
#pragma unroll
    for (int m = 1; m < 64; m <<= 1) {
        s0 += __shfl_xor(s0, m); q0 += __shfl_xor(q0, m);
        s1 += __shfl_xor(s1, m); q1 += __shfl_xor(q1, m);
    }
    float m0 = s0 * (1.f / 256.f), m1 = s1 * (1.f / 256.f);
    float r0 = rsqrtf(q0 * (1.f / 256.f) - m0 * m0 + 1e-5f);
    float r1 = rsqrtf(q1 * (1.f / 256.f) - m1 * m1 + 1e-5f);
#pragma unroll
    for (int j = 0; j < 4; ++j) {
        int col = lane * 4 + j;
        float ga = g[col], ba = b[col];
        float h20 = (p0[j] - m0) * r0 * ga + ba;
        float h21 = (p1[j] - m1) * r1 * ga + ba;
        float val = (h20 + h21) * 0.5f;
        if (xb_out) xb_out[gbase + j] = f2bf(val);
        if (fout)   fout[gbase + j] = val;
    }
}

// ---------------- host ----------------
extern "C" void kernel_launch(void* const* d_in, const int* in_sizes, int n_in,
                              void* d_out, int out_size, void* d_ws, size_t ws_size,
                              hipStream_t stream) {
    const float* x0  = (const float*)d_in[0];
    const float* Wq  = (const float*)d_in[1];
    const float* bq  = (const float*)d_in[2];
    const float* Wk  = (const float*)d_in[3];
    const float* Wv  = (const float*)d_in[4];
    const float* Wo  = (const float*)d_in[5];
    const float* bo  = (const float*)d_in[6];
    const float* g1  = (const float*)d_in[7];
    const float* b1  = (const float*)d_in[8];
    const float* W1  = (const float*)d_in[9];
    const float* bf1 = (const float*)d_in[10];
    const float* W2  = (const float*)d_in[11];
    const float* bf2 = (const float*)d_in[12];
    const float* g2  = (const float*)d_in[13];
    const float* b2  = (const float*)d_in[14];
    const int* hs[3]  = {(const int*)d_in[15], (const int*)d_in[21], (const int*)d_in[27]};
    const int* ssx[3] = {(const int*)d_in[17], (const int*)d_in[23], (const int*)d_in[29]};
    const int* dsx[3] = {(const int*)d_in[19], (const int*)d_in[25], (const int*)d_in[31]};
    float* out = (float*)d_out;

    char* base = (char*)d_ws;
    size_t off = 0;
    auto carve = [&](size_t bytes) -> void* {
        void* r = base + off;
        off += (bytes + 255) & ~(size_t)255;
        return r;
    };
    // persistent: ~163 MB
    unsigned short* WqT  = (unsigned short*)carve((size_t)6 * 65536 * 2);
    unsigned short* WkvT = (unsigned short*)carve((size_t)6 * 131072 * 2);
    unsigned short* WoT  = (unsigned short*)carve((size_t)6 * 65536 * 2);
    unsigned short* W1F  = (unsigned short*)carve((size_t)6 * 262144 * 2);
    unsigned short* W2F  = (unsigned short*)carve((size_t)6 * 262144 * 2);
    unsigned short* xb   = (unsigned short*)carve((size_t)NTOT * DIM * 2);
    unsigned short* kvb  = (unsigned short*)carve((size_t)NTOT * 512 * 2);

    // chunk size: 3072 B per dst row (o01 1024 + tf 1024 + hb 1024; qc aliases tf)
    size_t avail = (ws_size > off + 8192) ? (ws_size - off - 8192) : 0;
    long rmax = (long)(avail / 3072);
    int R = (int)(rmax & ~63L);
    if (R < 1024)  R = 1024;
    if (R > 50048) R = 50048;

    unsigned short* o01  = (unsigned short*)carve((size_t)2 * R * DIM * 2);
    unsigned short* tfb  = (unsigned short*)carve((size_t)2 * R * DIM * 2);
    unsigned short* hbb  = (unsigned short*)carve((size_t)2 * R * DIM * 2);
    unsigned short* qc   = tfb; // alias: qc dead before tf is written

    // weight prep + input cast (graph-safe, deterministic)
    {
        int tot = 6 * 65536;
        dim3 g((tot + 255) / 256);
        transpose_cvt2<<<g, 256, 0, stream>>>(Wq, WqT, 256, 256, tot, 65536, 0);
        transpose_cvt2<<<g, 256, 0, stream>>>(Wk, WkvT, 256, 256, tot, 131072, 0);
        transpose_cvt2<<<g, 256, 0, stream>>>(Wv, WkvT, 256, 256, tot, 131072, 256);
        transpose_cvt2<<<g, 256, 0, stream>>>(Wo, WoT, 256, 256, tot, 65536, 0);
        int tot2 = 6 * 262144;
        dim3 g2d((tot2 + 255) / 256);
        pack_w1<<<g2d, 256, 0, stream>>>(W1, W1F, tot2);
        pack_w2<<<g2d, 256, 0, stream>>>(W2, W2F, tot2);
        int totx = NTOT * DIM;
        cvt_kernel<<<dim3((totx + 255) / 256), 256, 0, stream>>>(x0, xb, totx);
    }

    const int offs[3] = {0, NQn, NQn + NTn};
    const int ns[3]   = {NQn, NTn, NCn};
    const int ends[3] = {1, 2, 0};

    auto gemm = [&](const unsigned short* A, const unsigned short* BT, const float* bias,
                    unsigned short* C, int M, int N, int K, int relu) {
        dim3 g((M + 127) / 128, N / 128);
        gemm_bt<<<g, 256, 0, stream>>>(A, BT, bias, C, M, N, K, relu);
    };

    for (int l = 0; l < 2; ++l) {
        // fused K|V for all types
        for (int i = 0; i < 3; ++i) {
            int m = l * 3 + i;
            gemm(xb + (size_t)offs[i] * DIM, WkvT + (size_t)m * 131072, nullptr,
                 kvb + (size_t)offs[i] * 512, ns[i], 512, 256, 0);
        }
        // per-type, chunked pipeline (6 launches/chunk)
        for (int i = 0; i < 3; ++i) {
            int m = l * 3 + i;
            for (int r0 = 0; r0 < ns[i]; r0 += R) {
                int rc = ns[i] - r0 < R ? ns[i] - r0 : R;
                int goff = offs[i] + r0;
                gemm(xb + (size_t)goff * DIM, WqT + (size_t)m * 65536, bq + (size_t)m * 256,
                     qc, rc, 256, 256, 0);
                attn_kernel<<<dim3((rc + 3) / 4), 256, 0, stream>>>(
                    qc, kvb,
                    hs[i] + (size_t)r0 * DEG, ssx[i] + (size_t)r0 * DEG, dsx[i] + (size_t)r0 * DEG,
                    o01, rc, offs[i], offs[ends[i]]);
                gemm(o01, WoT + (size_t)m * 65536, bo + (size_t)m * 256, tfb, 2 * rc, 256, 256, 0);
                ln1_kernel<<<dim3((2 * rc + 3) / 4), 256, 0, stream>>>(
                    l == 0 ? x0 : nullptr, l == 0 ? nullptr : xb, tfb,
                    g1 + (size_t)m * 256, b1 + (size_t)m * 256, hbb, rc, goff);
                ffn_fused<<<dim3((2 * rc + 127) / 128), 256, 0, stream>>>(
                    hbb, W1F + (size_t)m * 262144, bf1 + (size_t)m * 1024,
                    W2F + (size_t)m * 262144, bf2 + (size_t)m * 256, tfb, 2 * rc);
                ln2_final<<<dim3((rc + 3) / 4), 256, 0, stream>>>(
                    hbb, tfb, g2 + (size_t)m * 256, b2 + (size_t)m * 256,
                    l == 0 ? xb : nullptr, l == 1 ? out : nullptr,
                    rc, goff);
            }
        }
    }
}

// Round 6
// 2613.589 us; speedup vs baseline: 1.4737x; 1.0145x over previous
//
#include <hip/hip_runtime.h>

#define NQn 40000
#define NTn 10000
#define NCn 50000
#define NTOT 100000
#define DIM 256
#define DEG 8

typedef __bf16 bf16x8 __attribute__((ext_vector_type(8)));
typedef float f32x4 __attribute__((ext_vector_type(4)));

#if __has_builtin(__builtin_amdgcn_exp2f)
#define EXP2F(x) __builtin_amdgcn_exp2f(x)
#else
#define EXP2F(x) exp2f(x)
#endif

static __device__ __forceinline__ float bf2f(unsigned short u) {
    union { unsigned int i; float f; } v; v.i = ((unsigned int)u) << 16; return v.f;
}
static __device__ __forceinline__ unsigned short f2bf(float f) {
    union { unsigned int i; float f; } v; v.f = f;
    unsigned int u = v.i;
    return (unsigned short)((u + 0x7fffu + ((u >> 16) & 1u)) >> 16);
}

// ---------------- elementwise converts ----------------
__global__ void cvt_kernel(const float* __restrict__ in, unsigned short* __restrict__ out, int n) {
    int i = blockIdx.x * 256 + threadIdx.x;
    if (i < n) out[i] = f2bf(in[i]);
}

// W [m][K][NN] fp32 -> WT [m](row nn+nnoff)[K] bf16 with per-m out stride
__global__ void transpose_cvt2(const float* __restrict__ W, unsigned short* __restrict__ WT,
                               int K, int NN, int total, int ostride, int nnoff) {
    int i = blockIdx.x * 256 + threadIdx.x;
    if (i >= total) return;
    int per = K * NN;
    int m = i / per;
    int rem = i - m * per;
    int k = rem / NN;
    int nn = rem - k * NN;
    WT[(size_t)m * ostride + (size_t)(nn + nnoff) * K + k] = f2bf(W[i]);
}

// W1 [m][k=256][ucol=1024] fp32 -> fragment-linear pack for ffn phase1 A-operand.
// A-row m (= lane&15) maps to ucol = (m>>2)*8 + mi*4 + (m&3), so the phase-1
// C-fragment (row = q*4+reg) lands at ucol = c*32 + q*8 + mi*4 + reg: each lane
// then holds u-indices q*8..q*8+7 across the mi pair = EXACTLY the phase-2
// A-operand layout. u stays in registers (no LDS transpose).
__global__ void pack_w1(const float* __restrict__ W, unsigned short* __restrict__ P, int total) {
    int i = blockIdx.x * 256 + threadIdx.x;
    if (i >= total) return;
    int j  = i & 7;
    int l  = (i >> 3) & 63;
    int mi = (i >> 9) & 1;
    int kk = (i >> 10) & 7;
    int c  = (i >> 13) & 31;
    int m  = i >> 18;
    int r  = l & 15;
    int ucol = c * 32 + (r >> 2) * 8 + mi * 4 + (r & 3);
    int k    = kk * 32 + (l >> 4) * 8 + j;
    P[i] = f2bf(W[((size_t)m * 256 + k) * 1024 + ucol]);
}

// W2 [m][u=1024][ocol=256] fp32 -> fragment-linear pack for ffn phase2 B-operand:
// P[m][c:32][nf:16][lane:64][j:8]; elem (ocol = nf*16+(lane&15), u = c*32+(lane>>4)*8+j)
__global__ void pack_w2(const float* __restrict__ W, unsigned short* __restrict__ P, int total) {
    int i = blockIdx.x * 256 + threadIdx.x;
    if (i >= total) return;
    int j  = i & 7;
    int l  = (i >> 3) & 63;
    int nf = (i >> 9) & 15;
    int c  = (i >> 13) & 31;
    int m  = i >> 18;
    int ocol = nf * 16 + (l & 15);
    int u    = c * 32 + (l >> 4) * 8 + j;
    P[i] = f2bf(W[((size_t)m * 1024 + u) * 256 + ocol]);
}

// ---------------- GEMM: C[M,N](bf16) = A[M,K](bf16) @ BT[N,K](bf16)^T (+bias, opt relu) ----
__global__ __launch_bounds__(256) void gemm_bt(
    const unsigned short* __restrict__ A,
    const unsigned short* __restrict__ BT,
    const float* __restrict__ bias,
    unsigned short* __restrict__ C,
    int M, int N, int K, int relu)
{
    __shared__ unsigned short a_lds[128 * 32];
    __shared__ unsigned short b_lds[128 * 32];
    const int tid  = threadIdx.x;
    const int w    = tid >> 6;
    const int lane = tid & 63;
    const int rb = blockIdx.x * 128;
    const int cb = blockIdx.y * 128;
    const int wrow = (w & 1) * 64;
    const int wcol = (w >> 1) * 64;
    const int q   = lane >> 4;   // 0..3
    const int r16 = lane & 15;

    f32x4 acc[4][4];
#pragma unroll
    for (int i = 0; i < 4; ++i)
#pragma unroll
        for (int j = 0; j < 4; ++j) acc[i][j] = f32x4{0.f, 0.f, 0.f, 0.f};

    for (int k0 = 0; k0 < K; k0 += 32) {
        __syncthreads();
#pragma unroll
        for (int it = 0; it < 2; ++it) {
            int fl  = it * 256 + tid;
            int row = fl >> 2;
            int c8  = (fl & 3) * 8;
            int arow = rb + row; if (arow > M - 1) arow = M - 1;
            const unsigned short* ga = A  + (size_t)arow * K + k0 + c8;
            const unsigned short* gb = BT + (size_t)(cb + row) * K + k0 + c8;
            unsigned short* la = &a_lds[(size_t)(it * 256 + (tid & ~63)) * 8];
            unsigned short* lb = &b_lds[(size_t)(it * 256 + (tid & ~63)) * 8];
            __builtin_amdgcn_global_load_lds((const __attribute__((address_space(1))) void*)ga,
                                             (__attribute__((address_space(3))) void*)la, 16, 0, 0);
            __builtin_amdgcn_global_load_lds((const __attribute__((address_space(1))) void*)gb,
                                             (__attribute__((address_space(3))) void*)lb, 16, 0, 0);
        }
        __syncthreads();
        bf16x8 af[4], bfr[4];
#pragma unroll
        for (int mi = 0; mi < 4; ++mi)
            af[mi] = *(const bf16x8*)&a_lds[(wrow + mi * 16 + r16) * 32 + q * 8];
#pragma unroll
        for (int ni = 0; ni < 4; ++ni)
            bfr[ni] = *(const bf16x8*)&b_lds[(wcol + ni * 16 + r16) * 32 + q * 8];
#pragma unroll
        for (int mi = 0; mi < 4; ++mi)
#pragma unroll
            for (int ni = 0; ni < 4; ++ni)
                acc[mi][ni] = __builtin_amdgcn_mfma_f32_16x16x32_bf16(af[mi], bfr[ni], acc[mi][ni], 0, 0, 0);
    }

#pragma unroll
    for (int mi = 0; mi < 4; ++mi) {
#pragma unroll
        for (int ni = 0; ni < 4; ++ni) {
            int col = cb + wcol + ni * 16 + r16;
            float bv = bias ? bias[col] : 0.f;
#pragma unroll
            for (int rr = 0; rr < 4; ++rr) {
                int row = rb + wrow + mi * 16 + q * 4 + rr;
                if (row < M) {
                    float v = acc[mi][ni][rr] + bv;
                    if (relu && v < 0.f) v = 0.f;
                    C[(size_t)row * N + col] = f2bf(v);
                }
            }
        }
    }
}

// ---------------- fused FFN: f = relu(h @ W1 + b1) @ W2 + b2 -------------------
// v3: u NEVER touches LDS. pack_w1's ucol mapping makes the phase-1 accumulator
// land per-lane in phase-2 A-operand order (u = q*8..q*8+7 of own row), so
// bias+relu+f2bf+pack happen in registers between the two MFMA phases.
// Per chunk per wave: 16 W1 reads -> 32 MFMA; 16 W2 reads + 2 b1 broadcast
// reads -> 32 MFMA; zero ds_writes, zero transpose round-trip. LDS 36KB.
// Numerically bit-identical to the round-5 kernel (same sums, same rounding).
__global__ __launch_bounds__(256, 2) void ffn_fused(
    const unsigned short* __restrict__ hbp,
    const unsigned short* __restrict__ w1f,
    const float* __restrict__ b1p,
    const unsigned short* __restrict__ w2f,
    const float* __restrict__ b2p,
    unsigned short* __restrict__ fout,
    int M)
{
    __shared__ __align__(16) unsigned short w1_lds[8192];   // 16KB: chunk frag-linear
    __shared__ __align__(16) unsigned short w2_lds[8192];   // 16KB
    __shared__ __align__(16) float b1_lds[1024];            // 4KB

    const int tid  = threadIdx.x;
    const int lane = tid & 63;
    const int q    = lane >> 4;   // 0..3
    const int r16  = lane & 15;
    const int row0 = blockIdx.x * 128 + (tid >> 6) * 32;

    // ---- prologue: hoist h fragments (global->reg), stage b1 (global->LDS)
    bf16x8 hf[2][8];
#pragma unroll
    for (int nj = 0; nj < 2; ++nj) {
        int rrow = row0 + nj * 16 + r16;
        if (rrow > M - 1) rrow = M - 1;
        const unsigned short* hr = hbp + (size_t)rrow * DIM;
#pragma unroll
        for (int kk = 0; kk < 8; ++kk)
            hf[nj][kk] = *(const bf16x8*)&hr[kk * 32 + q * 8];
    }
    {
        const float* g = b1p + tid * 4;                      // 1024 floats, 16B/lane
        float* l = &b1_lds[(tid & ~63) * 4];                 // wave-uniform dest base
        __builtin_amdgcn_global_load_lds((const __attribute__((address_space(1))) void*)g,
                                         (__attribute__((address_space(3))) void*)l, 16, 0, 0);
    }

    f32x4 acc[2][16];
#pragma unroll
    for (int nj = 0; nj < 2; ++nj)
#pragma unroll
        for (int nf = 0; nf < 16; ++nf) acc[nj][nf] = f32x4{0.f, 0.f, 0.f, 0.f};

    for (int c = 0; c < 32; ++c) {
        __syncthreads();   // all waves done reading previous chunk's LDS
#pragma unroll
        for (int it = 0; it < 4; ++it) {
            int fl = it * 256 + tid;
            const unsigned short* g = w1f + (size_t)c * 8192 + (size_t)fl * 8;
            unsigned short* l = &w1_lds[(size_t)(it * 256 + (tid & ~63)) * 8];
            __builtin_amdgcn_global_load_lds((const __attribute__((address_space(1))) void*)g,
                                             (__attribute__((address_space(3))) void*)l, 16, 0, 0);
        }
#pragma unroll
        for (int it = 0; it < 4; ++it) {
            int fl = it * 256 + tid;
            const unsigned short* g = w2f + (size_t)c * 8192 + (size_t)fl * 8;
            unsigned short* l = &w2_lds[(size_t)(it * 256 + (tid & ~63)) * 8];
            __builtin_amdgcn_global_load_lds((const __attribute__((address_space(1))) void*)g,
                                             (__attribute__((address_space(3))) void*)l, 16, 0, 0);
        }
        __syncthreads();   // staged chunk visible (compiler drains vmcnt here)

        // ---- phase 1: u^T = W1c (A, frag-linear LDS) x h (B, regs)
        f32x4 au[2][2];
#pragma unroll
        for (int mi = 0; mi < 2; ++mi)
#pragma unroll
            for (int nj = 0; nj < 2; ++nj) au[mi][nj] = f32x4{0.f, 0.f, 0.f, 0.f};
#pragma unroll
        for (int kk = 0; kk < 8; ++kk) {
#pragma unroll
            for (int mi = 0; mi < 2; ++mi) {
                bf16x8 a = *(const bf16x8*)&w1_lds[(size_t)((kk * 2 + mi) * 64 + lane) * 8];
#pragma unroll
                for (int nj = 0; nj < 2; ++nj)
                    au[mi][nj] = __builtin_amdgcn_mfma_f32_16x16x32_bf16(a, hf[nj][kk], au[mi][nj], 0, 0, 0);
            }
        }

        // ---- bias + relu + bf16 pack, ALL IN REGISTERS.
        // Lane (r16,q) holds u-indices c*32 + q*8 + {0..7} of rows nj*16+r16:
        // elems 0..3 from au[0] (+b1[c*32+q*8+0..3]), 4..7 from au[1] (+...4..7).
        f32x4 bv0 = *(const f32x4*)&b1_lds[c * 32 + q * 8];
        f32x4 bv1 = *(const f32x4*)&b1_lds[c * 32 + q * 8 + 4];
        bf16x8 uf[2];
#pragma unroll
        for (int nj = 0; nj < 2; ++nj) {
            union { bf16x8 v; unsigned short s[8]; } up;
#pragma unroll
            for (int j = 0; j < 4; ++j) {
                up.s[j]     = f2bf(fmaxf(au[0][nj][j] + bv0[j], 0.f));
                up.s[4 + j] = f2bf(fmaxf(au[1][nj][j] + bv1[j], 0.f));
            }
            uf[nj] = up.v;
        }

        // ---- phase 2: acc += u (A, regs) x W2c (B, frag-linear LDS)
#pragma unroll
        for (int nf = 0; nf < 16; ++nf) {
            bf16x8 b = *(const bf16x8*)&w2_lds[(size_t)(nf * 64 + lane) * 8];
#pragma unroll
            for (int nj = 0; nj < 2; ++nj)
                acc[nj][nf] = __builtin_amdgcn_mfma_f32_16x16x32_bf16(uf[nj], b, acc[nj][nf], 0, 0, 0);
        }
    }

    // ---- epilogue: + b2, store bf16
#pragma unroll
    for (int nf = 0; nf < 16; ++nf) {
        int col = nf * 16 + r16;
        float bv = b2p[col];
#pragma unroll
        for (int nj = 0; nj < 2; ++nj) {
#pragma unroll
            for (int rr = 0; rr < 4; ++rr) {
                int row = row0 + nj * 16 + q * 4 + rr;
                if (row < M) fout[(size_t)row * DIM + col] = f2bf(acc[nj][nf][rr] + bv);
            }
        }
    }
}

// ---------------- attention: one wave per dst node (chunked) ----------------
// kv layout: per node 512 elems: [0,256) = k, [256,512) = v
__device__ __forceinline__ void attn_accum(
    const unsigned short* __restrict__ kvb,
    const int4 s0, const int4 s1, int off_s, int hc,
    const float qv[4], float wv[4], float& z)
{
    const int sidx[8] = {s0.x, s0.y, s0.z, s0.w, s1.x, s1.y, s1.z, s1.w};
    const float CLAMP = 7.2134752f; // 5 * log2(e)
#pragma unroll
    for (int e = 0; e < DEG; ++e) {
        size_t basep = ((size_t)(off_s + sidx[e]) * 512) + hc;
        ushort4 k4 = *(const ushort4*)&kvb[basep];
        float dot = qv[0] * bf2f(k4.x) + qv[1] * bf2f(k4.y) + qv[2] * bf2f(k4.z) + qv[3] * bf2f(k4.w);
        dot += __shfl_xor(dot, 1);
        dot += __shfl_xor(dot, 2);
        dot += __shfl_xor(dot, 4);
        dot = fminf(fmaxf(dot, -CLAMP), CLAMP);
        float wgt = EXP2F(dot);
        ushort4 v4 = *(const ushort4*)&kvb[basep + 256];
        wv[0] += wgt * bf2f(v4.x);
        wv[1] += wgt * bf2f(v4.y);
        wv[2] += wgt * bf2f(v4.z);
        wv[3] += wgt * bf2f(v4.w);
        z += wgt;
    }
}

// qc: chunk-local q rows; writes o01: rows [0,rc)=o0, rows [rc,2rc)=o1
__global__ __launch_bounds__(256) void attn_kernel(
    const unsigned short* __restrict__ qc,
    const unsigned short* __restrict__ kvb,
    const int* __restrict__ src_h,
    const int* __restrict__ src_s,
    const int* __restrict__ src_d,
    unsigned short* __restrict__ o01,
    int rc, int off_d, int off_j)
{
    int widx = (int)((blockIdx.x * 256 + threadIdx.x) >> 6);
    if (widx >= rc) return;
    int lane = threadIdx.x & 63;
    int hc = (lane >> 3) * 32 + (lane & 7) * 4;
    const float PRESCALE = 0.17677669529663687f * 1.4426950408889634f; // 1/sqrt(32)*log2e
    float qv[4];
    {
        ushort4 t4 = *(const ushort4*)&qc[(size_t)widx * DIM + hc];
        qv[0] = bf2f(t4.x) * PRESCALE; qv[1] = bf2f(t4.y) * PRESCALE;
        qv[2] = bf2f(t4.z) * PRESCALE; qv[3] = bf2f(t4.w) * PRESCALE;
    }
    int4 h0 = *(const int4*)&src_h[widx * DEG];
    int4 h1 = *(const int4*)&src_h[widx * DEG + 4];
    int4 ss0 = *(const int4*)&src_s[widx * DEG];
    int4 ss1 = *(const int4*)&src_s[widx * DEG + 4];
    int4 d0 = *(const int4*)&src_d[widx * DEG];
    int4 d1 = *(const int4*)&src_d[widx * DEG + 4];

    size_t ob = (size_t)widx * DIM + hc;

    float wv[4] = {0.f, 0.f, 0.f, 0.f}; float z = 0.f;
    attn_accum(kvb, h0, h1, off_d, hc, qv, wv, z);
    float inv = 1.f / (z + 1e-9f);
    o01[ob + 0] = f2bf(wv[0] * inv); o01[ob + 1] = f2bf(wv[1] * inv);
    o01[ob + 2] = f2bf(wv[2] * inv); o01[ob + 3] = f2bf(wv[3] * inv);

    wv[0] = wv[1] = wv[2] = wv[3] = 0.f; z = 0.f;
    attn_accum(kvb, ss0, ss1, off_j, hc, qv, wv, z);
    attn_accum(kvb, d0, d1, off_d, hc, qv, wv, z);
    inv = 1.f / (z + 1e-9f);
    size_t ob1 = ob + (size_t)rc * DIM;
    o01[ob1 + 0] = f2bf(wv[0] * inv); o01[ob1 + 1] = f2bf(wv[1] * inv);
    o01[ob1 + 2] = f2bf(wv[2] * inv); o01[ob1 + 3] = f2bf(wv[3] * inv);
}

// ---------------- LN1 over 2rc rows (both metapaths share the x residual) ----------------
__global__ __launch_bounds__(256) void ln1_kernel(
    const float* __restrict__ xres_f, const unsigned short* __restrict__ xres_b,
    const unsigned short* __restrict__ t,
    const float* __restrict__ g, const float* __restrict__ b,
    unsigned short* __restrict__ hb,
    int rc, int goff)
{
    int row = (int)((blockIdx.x * 256 + threadIdx.x) >> 6);
    int n2 = 2 * rc;
    if (row >= n2) return;
    int lane = threadIdx.x & 63;
    int dstrow = row < rc ? row : row - rc;
    size_t gbase = (size_t)(goff + dstrow) * DIM + lane * 4;
    size_t lbase = (size_t)row * DIM + lane * 4;
    float pre[4];
#pragma unroll
    for (int j = 0; j < 4; ++j) {
        float xr = xres_f ? xres_f[gbase + j] : bf2f(xres_b[gbase + j]);
        pre[j] = xr + bf2f(t[lbase + j]);
    }
    float s = 0.f, sq = 0.f;
#pragma unroll
    for (int j = 0; j < 4; ++j) { s += pre[j]; sq += pre[j] * pre[j]; }
#pragma unroll
    for (int m = 1; m < 64; m <<= 1) { s += __shfl_xor(s, m); sq += __shfl_xor(sq, m); }
    float mean = s * (1.f / 256.f);
    float var = sq * (1.f / 256.f) - mean * mean;
    float rstd = rsqrtf(var + 1e-5f);
#pragma unroll
    for (int j = 0; j < 4; ++j) {
        int col = lane * 4 + j;
        float hv = (pre[j] - mean) * rstd * g[col] + b[col];
        hb[lbase + j] = f2bf(hv);
    }
}

// ---------------- LN2 + metapath mean: wave per dst row, reads both halves ----------------
__global__ __launch_bounds__(256) void ln2_final(
    const unsigned short* __restrict__ hb, const unsigned short* __restrict__ f,
    const float* __restrict__ g, const float* __restrict__ b,
    unsigned short* __restrict__ xb_out,   // layer0: next-layer bf16 x
    float* __restrict__ fout,              // layer1: d_out
    int rc, int goff)
{
    int row = (int)((blockIdx.x * 256 + threadIdx.x) >> 6);
    if (row >= rc) return;
    int lane = threadIdx.x & 63;
    size_t lb0 = (size_t)row * DIM + lane * 4;
    size_t lb1 = (size_t)(rc + row) * DIM + lane * 4;
    size_t gbase = (size_t)(goff + row) * DIM + lane * 4;
    float p0[4], p1[4];
#pragma unroll
    for (int j = 0; j < 4; ++j) {
        p0[j] = bf2f(hb[lb0 + j]) + bf2f(f[lb0 + j]);
        p1[j] = bf2f(hb[lb1 + j]) + bf2f(f[lb1 + j]);
    }
    float s0 = 0.f, q0 = 0.f, s1 = 0.f, q1 = 0.f;
#pragma unroll
    for (int j = 0; j < 4; ++j) {
        s0 += p0[j]; q0 += p0[j] * p0[j];
        s1 += p1[j]; q1 += p1[j] * p1[j];
    }
#pragma unroll
    for (int m = 1; m < 64; m <<= 1) {
        s0 += __shfl_xor(s0, m); q0 += __shfl_xor(q0, m);
        s1 += __shfl_xor(s1, m); q1 += __shfl_xor(q1, m);
    }
    float m0 = s0 * (1.f / 256.f), m1 = s1 * (1.f / 256.f);
    float r0 = rsqrtf(q0 * (1.f / 256.f) - m0 * m0 + 1e-5f);
    float r1 = rsqrtf(q1 * (1.f / 256.f) - m1 * m1 + 1e-5f);
#pragma unroll
    for (int j = 0; j < 4; ++j) {
        int col = lane * 4 + j;
        float ga = g[col], ba = b[col];
        float h20 = (p0[j] - m0) * r0 * ga + ba;
        float h21 = (p1[j] - m1) * r1 * ga + ba;
        float val = (h20 + h21) * 0.5f;
        if (xb_out) xb_out[gbase + j] = f2bf(val);
        if (fout)   fout[gbase + j] = val;
    }
}

// ---------------- host ----------------
extern "C" void kernel_launch(void* const* d_in, const int* in_sizes, int n_in,
                              void* d_out, int out_size, void* d_ws, size_t ws_size,
                              hipStream_t stream) {
    const float* x0  = (const float*)d_in[0];
    const float* Wq  = (const float*)d_in[1];
    const float* bq  = (const float*)d_in[2];
    const float* Wk  = (const float*)d_in[3];
    const float* Wv  = (const float*)d_in[4];
    const float* Wo  = (const float*)d_in[5];
    const float* bo  = (const float*)d_in[6];
    const float* g1  = (const float*)d_in[7];
    const float* b1  = (const float*)d_in[8];
    const float* W1  = (const float*)d_in[9];
    const float* bf1 = (const float*)d_in[10];
    const float* W2  = (const float*)d_in[11];
    const float* bf2 = (const float*)d_in[12];
    const float* g2  = (const float*)d_in[13];
    const float* b2  = (const float*)d_in[14];
    const int* hs[3]  = {(const int*)d_in[15], (const int*)d_in[21], (const int*)d_in[27]};
    const int* ssx[3] = {(const int*)d_in[17], (const int*)d_in[23], (const int*)d_in[29]};
    const int* dsx[3] = {(const int*)d_in[19], (const int*)d_in[25], (const int*)d_in[31]};
    float* out = (float*)d_out;

    char* base = (char*)d_ws;
    size_t off = 0;
    auto carve = [&](size_t bytes) -> void* {
        void* r = base + off;
        off += (bytes + 255) & ~(size_t)255;
        return r;
    };
    // persistent: ~163 MB
    unsigned short* WqT  = (unsigned short*)carve((size_t)6 * 65536 * 2);
    unsigned short* WkvT = (unsigned short*)carve((size_t)6 * 131072 * 2);
    unsigned short* WoT  = (unsigned short*)carve((size_t)6 * 65536 * 2);
    unsigned short* W1F  = (unsigned short*)carve((size_t)6 * 262144 * 2);
    unsigned short* W2F  = (unsigned short*)carve((size_t)6 * 262144 * 2);
    unsigned short* xb   = (unsigned short*)carve((size_t)NTOT * DIM * 2);
    unsigned short* kvb  = (unsigned short*)carve((size_t)NTOT * 512 * 2);

    // chunk size: 3072 B per dst row (o01 1024 + tf 1024 + hb 1024; qc aliases tf)
    size_t avail = (ws_size > off + 8192) ? (ws_size - off - 8192) : 0;
    long rmax = (long)(avail / 3072);
    int R = (int)(rmax & ~63L);
    if (R < 1024)  R = 1024;
    if (R > 50048) R = 50048;

    unsigned short* o01  = (unsigned short*)carve((size_t)2 * R * DIM * 2);
    unsigned short* tfb  = (unsigned short*)carve((size_t)2 * R * DIM * 2);
    unsigned short* hbb  = (unsigned short*)carve((size_t)2 * R * DIM * 2);
    unsigned short* qc   = tfb; // alias: qc dead before tf is written

    // weight prep + input cast (graph-safe, deterministic)
    {
        int tot = 6 * 65536;
        dim3 g((tot + 255) / 256);
        transpose_cvt2<<<g, 256, 0, stream>>>(Wq, WqT, 256, 256, tot, 65536, 0);
        transpose_cvt2<<<g, 256, 0, stream>>>(Wk, WkvT, 256, 256, tot, 131072, 0);
        transpose_cvt2<<<g, 256, 0, stream>>>(Wv, WkvT, 256, 256, tot, 131072, 256);
        transpose_cvt2<<<g, 256, 0, stream>>>(Wo, WoT, 256, 256, tot, 65536, 0);
        int tot2 = 6 * 262144;
        dim3 g2d((tot2 + 255) / 256);
        pack_w1<<<g2d, 256, 0, stream>>>(W1, W1F, tot2);
        pack_w2<<<g2d, 256, 0, stream>>>(W2, W2F, tot2);
        int totx = NTOT * DIM;
        cvt_kernel<<<dim3((totx + 255) / 256), 256, 0, stream>>>(x0, xb, totx);
    }

    const int offs[3] = {0, NQn, NQn + NTn};
    const int ns[3]   = {NQn, NTn, NCn};
    const int ends[3] = {1, 2, 0};

    auto gemm = [&](const unsigned short* A, const unsigned short* BT, const float* bias,
                    unsigned short* C, int M, int N, int K, int relu) {
        dim3 g((M + 127) / 128, N / 128);
        gemm_bt<<<g, 256, 0, stream>>>(A, BT, bias, C, M, N, K, relu);
    };

    for (int l = 0; l < 2; ++l) {
        // fused K|V for all types
        for (int i = 0; i < 3; ++i) {
            int m = l * 3 + i;
            gemm(xb + (size_t)offs[i] * DIM, WkvT + (size_t)m * 131072, nullptr,
                 kvb + (size_t)offs[i] * 512, ns[i], 512, 256, 0);
        }
        // per-type, chunked pipeline (6 launches/chunk)
        for (int i = 0; i < 3; ++i) {
            int m = l * 3 + i;
            for (int r0 = 0; r0 < ns[i]; r0 += R) {
                int rc = ns[i] - r0 < R ? ns[i] - r0 : R;
                int goff = offs[i] + r0;
                gemm(xb + (size_t)goff * DIM, WqT + (size_t)m * 65536, bq + (size_t)m * 256,
                     qc, rc, 256, 256, 0);
                attn_kernel<<<dim3((rc + 3) / 4), 256, 0, stream>>>(
                    qc, kvb,
                    hs[i] + (size_t)r0 * DEG, ssx[i] + (size_t)r0 * DEG, dsx[i] + (size_t)r0 * DEG,
                    o01, rc, offs[i], offs[ends[i]]);
                gemm(o01, WoT + (size_t)m * 65536, bo + (size_t)m * 256, tfb, 2 * rc, 256, 256, 0);
                ln1_kernel<<<dim3((2 * rc + 3) / 4), 256, 0, stream>>>(
                    l == 0 ? x0 : nullptr, l == 0 ? nullptr : xb, tfb,
                    g1 + (size_t)m * 256, b1 + (size_t)m * 256, hbb, rc, goff);
                ffn_fused<<<dim3((2 * rc + 127) / 128), 256, 0, stream>>>(
                    hbb, W1F + (size_t)m * 262144, bf1 + (size_t)m * 1024,
                    W2F + (size_t)m * 262144, bf2 + (size_t)m * 256, tfb, 2 * rc);
                ln2_final<<<dim3((rc + 3) / 4), 256, 0, stream>>>(
                    hbb, tfb, g2 + (size_t)m * 256, b2 + (size_t)m * 256,
                    l == 0 ? xb : nullptr, l == 1 ? out : nullptr,
                    rc, goff);
            }
        }
    }
}